// Round 18
// baseline (48.739 us; speedup 1.0000x reference)
//
#include <hip/hip_runtime.h>
#include <hip/hip_bf16.h>

#define BT 16      // B*T
#define NN 256     // nodes
#define DD 128     // feature dim

typedef __bf16 bf16x8 __attribute__((ext_vector_type(8)));
typedef __bf16 bf16x2 __attribute__((ext_vector_type(2)));
typedef float  f32x4  __attribute__((ext_vector_type(4)));

#define LREL(z) ((z) >= 0.0f ? (z) : 0.2f * (z))
#define HSP 136    // hs row stride (bf16): padded -> MFMA frag reads 2-way max
// LDS: hs[256][136] + bs[256][128] + as_[16][136] bf16 + nbrl[16][64] int
#define LDS_BYTES (256*HSP*2 + 256*DD*2 + 16*HSP*2 + 16*64*4)   // 143,616 B

// ==== Single fused kernel: block = (bt, 16-node group), 1024 thr, 16 waves =
// Wave w owns col-tile (w&7) and row-half (w>>3): B-frags loaded ONCE,
// reused across 8 row-tiles (fixes R12's 544-strided-loads/wave pig).
//   phase 0 : own-node adjacency compaction (overlaps weight-load latency)
//   phase 1 : h = x@W + bias (all 256 rows)          -> hs
//   phase 1b: b = h@W1b + att_b1 (all 256 rows)      -> bs
//   phase 1c: a = h@W1a (own 16 rows; waves 0-7)     -> as_
//   phase 2 : online-softmax attn + LN + ReLU, 1 node/wave, LDS reads only
__global__ __launch_bounds__(1024, 1) void fused_kernel(
        const float* __restrict__ x, const float* __restrict__ adj,
        const float* __restrict__ weight, const float* __restrict__ bias,
        const float* __restrict__ attw1, const float* __restrict__ attb1,
        const float* __restrict__ w2, const float* __restrict__ gamma,
        const float* __restrict__ beta, float* __restrict__ out) {
    extern __shared__ char smem[];
    __bf16* hs   = (__bf16*)smem;             // [256][HSP]
    __bf16* bs   = hs + 256 * HSP;            // [256][DD]
    __bf16* as_  = bs + 256 * DD;             // [16][HSP]
    int*    nbrl = (int*)(as_ + 16 * HSP);    // [16][64]

    int tid = threadIdx.x;
    int w = tid >> 6, l = tid & 63;           // w in [0,16)
    int bt = blockIdx.x >> 4, grp = blockIdx.x & 15;
    int lrow = l & 15, lk8 = (l >> 4) * 8;
    int rsub = (l >> 4) * 4;                  // MFMA D: row = rsub+r, col = lrow

    // ---- phase 0: adjacency compaction for this wave's node ----
    int i_node = grp * 16 + w;
    int cnt = 0;
    {
        const float* adjrow = adj + (size_t)i_node * NN;
        for (int jt = 0; jt < NN / 64; ++jt) {
            int j = jt * 64 + l;
            float v = adjrow[j];
            unsigned long long mask = __ballot(v != 0.f);
            if (v != 0.f) {
                int pos = cnt + __popcll(mask & ((1ull << l) - 1ull));
                if (pos < 64) nbrl[w * 64 + pos] = j;
            }
            cnt += __popcll(mask);
        }
        cnt = min(cnt, 64);
    }

    int ct = w & 7, half = w >> 3;
    int ncol = ct * 16 + lrow;

    // ---- B-frags, loaded once per wave (strided fp32, L2-hot) ----
    bf16x8 wf[4], w1bf[4];
#pragma unroll
    for (int kt = 0; kt < 4; ++kt) {
        const float* wp = weight + (size_t)(lk8 + 32 * kt) * DD + ncol;
        const float* bp = attw1 + (size_t)(DD + lk8 + 32 * kt) * DD + ncol;
#pragma unroll
        for (int j = 0; j < 8; ++j) {
            wf[kt][j]   = (__bf16)wp[(size_t)j * DD];
            w1bf[kt][j] = (__bf16)bp[(size_t)j * DD];
        }
    }
    bf16x8 w1af[4];
    if (w < 8) {                              // phase-1c frag, hoisted
#pragma unroll
        for (int kt = 0; kt < 4; ++kt) {
            const float* ap = attw1 + (size_t)(lk8 + 32 * kt) * DD + (w * 16 + lrow);
#pragma unroll
            for (int j = 0; j < 8; ++j)
                w1af[kt][j] = (__bf16)ap[(size_t)j * DD];
        }
    }

    // ---- phase 1: h row-tiles half*8 .. half*8+7, col-tile ct ----
    float bb = bias[ncol];
#pragma unroll
    for (int rt8 = 0; rt8 < 8; ++rt8) {
        int rt = half * 8 + rt8;
        const float* abase = x + ((size_t)bt * NN + rt * 16 + lrow) * DD + lk8;
        bf16x8 af[4];
#pragma unroll
        for (int kt = 0; kt < 4; ++kt) {
            float4 u0 = *(const float4*)(abase + 32 * kt);
            float4 u1 = *(const float4*)(abase + 32 * kt + 4);
            af[kt][0]=(__bf16)u0.x; af[kt][1]=(__bf16)u0.y;
            af[kt][2]=(__bf16)u0.z; af[kt][3]=(__bf16)u0.w;
            af[kt][4]=(__bf16)u1.x; af[kt][5]=(__bf16)u1.y;
            af[kt][6]=(__bf16)u1.z; af[kt][7]=(__bf16)u1.w;
        }
        f32x4 acc = {0.f, 0.f, 0.f, 0.f};
        acc = __builtin_amdgcn_mfma_f32_16x16x32_bf16(af[0], wf[0], acc, 0, 0, 0);
        acc = __builtin_amdgcn_mfma_f32_16x16x32_bf16(af[1], wf[1], acc, 0, 0, 0);
        acc = __builtin_amdgcn_mfma_f32_16x16x32_bf16(af[2], wf[2], acc, 0, 0, 0);
        acc = __builtin_amdgcn_mfma_f32_16x16x32_bf16(af[3], wf[3], acc, 0, 0, 0);
        int row0 = rt * 16 + rsub;
#pragma unroll
        for (int r = 0; r < 4; ++r)
            hs[(size_t)(row0 + r) * HSP + ncol] = (__bf16)(acc[r] + bb);
    }
    __syncthreads();

    // ---- phase 1b: b row-tiles (A from hs), same col-tile ----
    float bb1 = attb1[ncol];
#pragma unroll
    for (int rt8 = 0; rt8 < 8; ++rt8) {
        int rt = half * 8 + rt8;
        bf16x8 ha[4];
#pragma unroll
        for (int kt = 0; kt < 4; ++kt)
            ha[kt] = *(const bf16x8*)&hs[(size_t)(rt * 16 + lrow) * HSP + lk8 + 32 * kt];
        f32x4 acc = {0.f, 0.f, 0.f, 0.f};
        acc = __builtin_amdgcn_mfma_f32_16x16x32_bf16(ha[0], w1bf[0], acc, 0, 0, 0);
        acc = __builtin_amdgcn_mfma_f32_16x16x32_bf16(ha[1], w1bf[1], acc, 0, 0, 0);
        acc = __builtin_amdgcn_mfma_f32_16x16x32_bf16(ha[2], w1bf[2], acc, 0, 0, 0);
        acc = __builtin_amdgcn_mfma_f32_16x16x32_bf16(ha[3], w1bf[3], acc, 0, 0, 0);
        int row0 = rt * 16 + rsub;
#pragma unroll
        for (int r = 0; r < 4; ++r)
            bs[(size_t)(row0 + r) * DD + ncol] = (__bf16)(acc[r] + bb1);
    }

    // ---- phase 1c: a for own 16 rows (waves 0-7, col-tile w) ----
    if (w < 8) {
        int ncol2 = w * 16 + lrow;
        bf16x8 hg[4];
#pragma unroll
        for (int kt = 0; kt < 4; ++kt)
            hg[kt] = *(const bf16x8*)&hs[(size_t)(grp * 16 + lrow) * HSP + lk8 + 32 * kt];
        f32x4 acc = {0.f, 0.f, 0.f, 0.f};
        acc = __builtin_amdgcn_mfma_f32_16x16x32_bf16(hg[0], w1af[0], acc, 0, 0, 0);
        acc = __builtin_amdgcn_mfma_f32_16x16x32_bf16(hg[1], w1af[1], acc, 0, 0, 0);
        acc = __builtin_amdgcn_mfma_f32_16x16x32_bf16(hg[2], w1af[2], acc, 0, 0, 0);
        acc = __builtin_amdgcn_mfma_f32_16x16x32_bf16(hg[3], w1af[3], acc, 0, 0, 0);
#pragma unroll
        for (int r = 0; r < 4; ++r)
            as_[(size_t)(rsub + r) * HSP + ncol2] = (__bf16)acc[r];
    }
    __syncthreads();

    // ---- phase 2: online-softmax attn + LN + ReLU (node i_node) ----
    int d2 = 2 * l;
    int jreg = nbrl[w * 64 + l];
    bf16x2 av = *(const bf16x2*)(as_ + (size_t)w * HSP + d2);
    float a0 = (float)av[0], a1 = (float)av[1];
    float2 wv = *(const float2*)(w2 + d2);
    float w20 = wv.x, w21 = wv.y;

    float m = -3.0e38f, dsum = 0.f, acc0 = 0.f, acc1 = 0.f;
    for (int c = 0; c < cnt; c += 4) {
        bool v1 = c + 1 < cnt, v2 = c + 2 < cnt, v3 = c + 3 < cnt;
        int j0 = __shfl(jreg, c);
        int j1 = v1 ? __shfl(jreg, c + 1) : i_node;
        int j2 = v2 ? __shfl(jreg, c + 2) : i_node;
        int j3 = v3 ? __shfl(jreg, c + 3) : i_node;
        bf16x2 b0 = *(const bf16x2*)(bs + (size_t)j0 * DD + d2);
        bf16x2 b1 = *(const bf16x2*)(bs + (size_t)j1 * DD + d2);
        bf16x2 b2 = *(const bf16x2*)(bs + (size_t)j2 * DD + d2);
        bf16x2 b3 = *(const bf16x2*)(bs + (size_t)j3 * DD + d2);
        bf16x2 h0 = *(const bf16x2*)(hs + (size_t)j0 * HSP + d2);
        bf16x2 h1 = *(const bf16x2*)(hs + (size_t)j1 * HSP + d2);
        bf16x2 h2 = *(const bf16x2*)(hs + (size_t)j2 * HSP + d2);
        bf16x2 h3 = *(const bf16x2*)(hs + (size_t)j3 * HSP + d2);

        float p0 = LREL(a0 + (float)b0[0]) * w20 + LREL(a1 + (float)b0[1]) * w21;
        float p1 = LREL(a0 + (float)b1[0]) * w20 + LREL(a1 + (float)b1[1]) * w21;
        float p2 = LREL(a0 + (float)b2[0]) * w20 + LREL(a1 + (float)b2[1]) * w21;
        float p3 = LREL(a0 + (float)b3[0]) * w20 + LREL(a1 + (float)b3[1]) * w21;
#pragma unroll
        for (int off = 32; off; off >>= 1) {
            p0 += __shfl_xor(p0, off);
            p1 += __shfl_xor(p1, off);
            p2 += __shfl_xor(p2, off);
            p3 += __shfl_xor(p3, off);
        }
        float pm1 = v1 ? p1 : -3.0e38f;
        float pm2 = v2 ? p2 : -3.0e38f;
        float pm3 = v3 ? p3 : -3.0e38f;
        float m_new = fmaxf(m, fmaxf(fmaxf(p0, pm1), fmaxf(pm2, pm3)));
        float scale = __expf(m - m_new);
        float e0 = __expf(p0 - m_new);
        float e1 = v1 ? __expf(p1 - m_new) : 0.f;
        float e2 = v2 ? __expf(p2 - m_new) : 0.f;
        float e3 = v3 ? __expf(p3 - m_new) : 0.f;
        dsum = dsum * scale + (e0 + e1) + (e2 + e3);
        acc0 = acc0 * scale + e0 * (float)h0[0] + e1 * (float)h1[0]
                            + e2 * (float)h2[0] + e3 * (float)h3[0];
        acc1 = acc1 * scale + e0 * (float)h0[1] + e1 * (float)h1[1]
                            + e2 * (float)h2[1] + e3 * (float)h3[1];
        m = m_new;
    }
    float inv = 1.f / dsum;                   // wave-uniform

    float2 xv = *(const float2*)(x + ((size_t)bt * NN + i_node) * DD + d2);
    float y0 = acc0 * inv + xv.x;
    float y1 = acc1 * inv + xv.y;

    float s = y0 + y1;
#pragma unroll
    for (int off = 32; off; off >>= 1) s += __shfl_xor(s, off);
    float mu = s * (1.0f / 128.0f);
    float v0 = y0 - mu, v1 = y1 - mu;
    float vs = v0 * v0 + v1 * v1;
#pragma unroll
    for (int off = 32; off; off >>= 1) vs += __shfl_xor(vs, off);
    float rstd = rsqrtf(vs * (1.0f / 128.0f) + 1e-5f);

    float2 gv = *(const float2*)(gamma + d2);
    float2 bv = *(const float2*)(beta + d2);
    float2 ov;
    ov.x = fmaxf(v0 * rstd * gv.x + bv.x, 0.0f);
    ov.y = fmaxf(v1 * rstd * gv.y + bv.y, 0.0f);
    *(float2*)(out + ((size_t)bt * NN + i_node) * DD + d2) = ov;
}

extern "C" void kernel_launch(void* const* d_in, const int* in_sizes, int n_in,
                              void* d_out, int out_size, void* d_ws, size_t ws_size,
                              hipStream_t stream) {
    const float* x      = (const float*)d_in[0];
    const float* adj    = (const float*)d_in[1];
    const float* weight = (const float*)d_in[2];
    const float* bias   = (const float*)d_in[3];
    const float* attw1  = (const float*)d_in[4];
    const float* attb1  = (const float*)d_in[5];
    const float* attw2  = (const float*)d_in[6];
    // d_in[7] = att_b2: uniform score shift -> cancels in softmax
    const float* gamma  = (const float*)d_in[8];
    const float* beta   = (const float*)d_in[9];
    float* out = (float*)d_out;

    fused_kernel<<<BT * 16, 1024, LDS_BYTES, stream>>>(
        x, adj, weight, bias, attw1, attb1, attw2, gamma, beta, out);
}

// Round 19
// 23.869 us; speedup vs baseline: 2.0420x; 2.0420x over previous
//
#include <hip/hip_runtime.h>
#include <hip/hip_bf16.h>

#define BT 16      // B*T
#define NN 256     // nodes
#define DD 128     // feature dim
#define MROWS (BT*NN)   // 4096 total rows

typedef __bf16 bf16x8 __attribute__((ext_vector_type(8)));
typedef __bf16 bf16x2 __attribute__((ext_vector_type(2)));
typedef float  f32x4  __attribute__((ext_vector_type(4)));

#define LREL(z) ((z) >= 0.0f ? (z) : 0.2f * (z))
#define HS_STRIDE 136   // bf16 elems per row: 272B, 16B-aligned rows

// ============ Kernel 1: two-stage GEMM + adjacency compaction =============
// 512 blocks x 256 thr. Block = (16-row chunk, parity); chunk in [0,256).
//   extra: wave 0 of parity-0 blocks compacts adjacency row `chunk` -> nbr
//   stage 1 (all blocks): h = x@W + bias -> LDS (bf16); parity 0 also -> hbuf
//   stage 2: parity 0 -> a = h@W1a ; parity 1 -> b = h@W1b + att_b1
// Session record: this structure (R15) = 24.18us. All perturbations tested
// (LDS weight transpose R13, 8-wave split R16, load hoist R17, fusion x4)
// were null or regressions -- the ~18us above body-work is 2x dispatch+drain
// floor, not addressable in-kernel.
__global__ __launch_bounds__(256) void gemm2_kernel(
        const float* __restrict__ x, const float* __restrict__ weight,
        const float* __restrict__ bias, const float* __restrict__ attw1,
        const float* __restrict__ attb1, const float* __restrict__ adj,
        __bf16* __restrict__ hbuf, __bf16* __restrict__ abuf,
        __bf16* __restrict__ bbuf, int* __restrict__ nbr,
        int* __restrict__ nbr_cnt) {
    int tid = threadIdx.x;
    int w = tid >> 6, l = tid & 63;
    int chunk = blockIdx.x >> 1, parity = blockIdx.x & 1;
    int row0 = chunk * 16;
    int lrow = l & 15, lk8 = (l >> 4) * 8;

    __shared__ __align__(16) __bf16 hs[16][HS_STRIDE];

    // ---- adjacency compaction for node `chunk` (wave 0, parity 0 only) ----
    if (parity == 0 && w == 0) {
        int i = chunk;                 // chunk spans [0,256) == all nodes
        int cnt = 0;
        const float* adjrow = adj + (size_t)i * NN;
        for (int jt = 0; jt < NN / 64; ++jt) {
            int j = jt * 64 + l;
            float v = adjrow[j];
            unsigned long long mask = __ballot(v != 0.f);
            if (v != 0.f) {
                int pos = cnt + __popcll(mask & ((1ull << l) - 1ull));
                if (pos < 64) nbr[i * 64 + pos] = j;
            }
            cnt += __popcll(mask);
        }
        if (l == 0) nbr_cnt[i] = min(cnt, 64);
    }

    // ---- A fragments from x: lane row (l&15), k = lk8 + 32*kt + j ----
    const float* abase = x + (size_t)(row0 + lrow) * DD + lk8;
    bf16x8 af[4];
#pragma unroll
    for (int kt = 0; kt < 4; ++kt) {
        float4 u0 = *(const float4*)(abase + 32 * kt);
        float4 u1 = *(const float4*)(abase + 32 * kt + 4);
        af[kt][0]=(__bf16)u0.x; af[kt][1]=(__bf16)u0.y;
        af[kt][2]=(__bf16)u0.z; af[kt][3]=(__bf16)u0.w;
        af[kt][4]=(__bf16)u1.x; af[kt][5]=(__bf16)u1.y;
        af[kt][6]=(__bf16)u1.z; af[kt][7]=(__bf16)u1.w;
    }

    // ---- stage 1: h tiles; wave w does n-tiles w and w+4 ----
#pragma unroll
    for (int s = 0; s < 2; ++s) {
        int n0 = (w + 4 * s) * 16;
        int ncol = n0 + lrow;
        bf16x8 wf[4];
#pragma unroll
        for (int kt = 0; kt < 4; ++kt) {
            const float* wp = weight + (size_t)(lk8 + 32 * kt) * DD + ncol;
#pragma unroll
            for (int j = 0; j < 8; ++j)
                wf[kt][j] = (__bf16)wp[(size_t)j * DD];
        }
        f32x4 acc = {0.f, 0.f, 0.f, 0.f};
        acc = __builtin_amdgcn_mfma_f32_16x16x32_bf16(af[0], wf[0], acc, 0, 0, 0);
        acc = __builtin_amdgcn_mfma_f32_16x16x32_bf16(af[1], wf[1], acc, 0, 0, 0);
        acc = __builtin_amdgcn_mfma_f32_16x16x32_bf16(af[2], wf[2], acc, 0, 0, 0);
        acc = __builtin_amdgcn_mfma_f32_16x16x32_bf16(af[3], wf[3], acc, 0, 0, 0);

        float bb = bias[ncol];
        int rloc = (l >> 4) * 4;               // D: row=(l>>4)*4+r, col=lane&15
        __bf16* hout = hbuf + (size_t)(row0 + rloc) * DD + ncol;
#pragma unroll
        for (int r = 0; r < 4; ++r) {
            __bf16 hv = (__bf16)(acc[r] + bb);
            hs[rloc + r][ncol] = hv;
            if (parity == 0) hout[(size_t)r * DD] = hv;
        }
    }
    __syncthreads();

    // ---- stage 2 (h2 = parity): a or b tiles from LDS h ----
    bf16x8 ha[4];
#pragma unroll
    for (int kt = 0; kt < 4; ++kt)
        ha[kt] = *(const bf16x8*)(&hs[lrow][lk8 + 32 * kt]);

#pragma unroll
    for (int s = 0; s < 2; ++s) {
        int n0 = (w + 4 * s) * 16;
        int ncol = n0 + lrow;
        bf16x8 w1f[4];
#pragma unroll
        for (int kt = 0; kt < 4; ++kt) {
            const float* wp = attw1 + (size_t)(parity * DD + lk8 + 32 * kt) * DD + ncol;
#pragma unroll
            for (int j = 0; j < 8; ++j)
                w1f[kt][j] = (__bf16)wp[(size_t)j * DD];
        }
        f32x4 acc = {0.f, 0.f, 0.f, 0.f};
        acc = __builtin_amdgcn_mfma_f32_16x16x32_bf16(ha[0], w1f[0], acc, 0, 0, 0);
        acc = __builtin_amdgcn_mfma_f32_16x16x32_bf16(ha[1], w1f[1], acc, 0, 0, 0);
        acc = __builtin_amdgcn_mfma_f32_16x16x32_bf16(ha[2], w1f[2], acc, 0, 0, 0);
        acc = __builtin_amdgcn_mfma_f32_16x16x32_bf16(ha[3], w1f[3], acc, 0, 0, 0);

        float bb = parity ? attb1[ncol] : 0.f;
        __bf16* dst = (parity ? bbuf : abuf) + (size_t)(row0 + (l >> 4) * 4) * DD + ncol;
#pragma unroll
        for (int r = 0; r < 4; ++r)
            dst[(size_t)r * DD] = (__bf16)(acc[r] + bb);
    }
}

// ============ Kernel 2: sparse attn, ONLINE softmax, + LN + ReLU ==========
// 4 waves/block, one (node, bt) per wave; lane l owns dims {2l, 2l+1}.
// Single neighbor loop: b-row and h-row loads issue together; running
// (m, dsum, acc) with rescale. Post-reduce scores are wave-uniform, so
// dsum needs no final reduction and no weight-ownership shuffles exist.
__global__ __launch_bounds__(256) void attn_kernel(
        const __bf16* __restrict__ hbuf, const __bf16* __restrict__ abuf,
        const __bf16* __restrict__ bbuf, const float* __restrict__ x,
        const int* __restrict__ nbr, const int* __restrict__ nbr_cnt,
        const float* __restrict__ w2, const float* __restrict__ gamma,
        const float* __restrict__ beta, float* __restrict__ out) {
    int tid = threadIdx.x;
    int w = tid >> 6, l = tid & 63;
    int i  = (blockIdx.x & 63) * 4 + w;
    int bt = blockIdx.x >> 6;
    int d2 = 2 * l;                 // this lane's dim pair {d2, d2+1}

    int cnt = nbr_cnt[i];
    int jreg = nbr[i * 64 + l];     // lane l holds neighbor l's index (l<cnt)

    bf16x2 av = *(const bf16x2*)(abuf + (size_t)(bt * NN + i) * DD + d2);
    float a0 = (float)av[0], a1 = (float)av[1];
    float2 wv = *(const float2*)(w2 + d2);
    float w20 = wv.x, w21 = wv.y;
    const __bf16* bbase = bbuf + (size_t)bt * NN * DD;
    const __bf16* hbase = hbuf + (size_t)bt * NN * DD;

    float m = -3.0e38f, dsum = 0.f, acc0 = 0.f, acc1 = 0.f;
    for (int c = 0; c < cnt; c += 4) {
        int i0 = c, i1 = c + 1, i2 = c + 2, i3 = c + 3;
        bool v1 = i1 < cnt, v2 = i2 < cnt, v3 = i3 < cnt;
        int j0 = __shfl(jreg, i0);
        int j1 = v1 ? __shfl(jreg, i1) : i;
        int j2 = v2 ? __shfl(jreg, i2) : i;
        int j3 = v3 ? __shfl(jreg, i3) : i;
        // b-rows and h-rows: 8 independent loads issued together
        bf16x2 b0 = *(const bf16x2*)(bbase + (size_t)j0 * DD + d2);
        bf16x2 b1 = *(const bf16x2*)(bbase + (size_t)j1 * DD + d2);
        bf16x2 b2 = *(const bf16x2*)(bbase + (size_t)j2 * DD + d2);
        bf16x2 b3 = *(const bf16x2*)(bbase + (size_t)j3 * DD + d2);
        bf16x2 h0 = *(const bf16x2*)(hbase + (size_t)j0 * DD + d2);
        bf16x2 h1 = *(const bf16x2*)(hbase + (size_t)j1 * DD + d2);
        bf16x2 h2 = *(const bf16x2*)(hbase + (size_t)j2 * DD + d2);
        bf16x2 h3 = *(const bf16x2*)(hbase + (size_t)j3 * DD + d2);

        float p0 = LREL(a0 + (float)b0[0]) * w20 + LREL(a1 + (float)b0[1]) * w21;
        float p1 = LREL(a0 + (float)b1[0]) * w20 + LREL(a1 + (float)b1[1]) * w21;
        float p2 = LREL(a0 + (float)b2[0]) * w20 + LREL(a1 + (float)b2[1]) * w21;
        float p3 = LREL(a0 + (float)b3[0]) * w20 + LREL(a1 + (float)b3[1]) * w21;
#pragma unroll
        for (int off = 32; off; off >>= 1) {
            p0 += __shfl_xor(p0, off);
            p1 += __shfl_xor(p1, off);
            p2 += __shfl_xor(p2, off);
            p3 += __shfl_xor(p3, off);
        }
        // online-softmax update (p* are wave-uniform now)
        float pm0 = p0;
        float pm1 = v1 ? p1 : -3.0e38f;
        float pm2 = v2 ? p2 : -3.0e38f;
        float pm3 = v3 ? p3 : -3.0e38f;
        float m_new = fmaxf(m, fmaxf(fmaxf(pm0, pm1), fmaxf(pm2, pm3)));
        float scale = __expf(m - m_new);
        float e0 = __expf(p0 - m_new);
        float e1 = v1 ? __expf(p1 - m_new) : 0.f;
        float e2 = v2 ? __expf(p2 - m_new) : 0.f;
        float e3 = v3 ? __expf(p3 - m_new) : 0.f;
        dsum = dsum * scale + (e0 + e1) + (e2 + e3);
        acc0 = acc0 * scale + e0 * (float)h0[0] + e1 * (float)h1[0]
                            + e2 * (float)h2[0] + e3 * (float)h3[0];
        acc1 = acc1 * scale + e0 * (float)h0[1] + e1 * (float)h1[1]
                            + e2 * (float)h2[1] + e3 * (float)h3[1];
        m = m_new;
    }
    float inv = 1.f / dsum;         // uniform across lanes, no reduce needed

    // ---- residual + LayerNorm + ReLU ----
    float2 xv = *(const float2*)(x + (size_t)(bt * NN + i) * DD + d2);
    float y0 = acc0 * inv + xv.x;
    float y1 = acc1 * inv + xv.y;

    float s = y0 + y1;
#pragma unroll
    for (int off = 32; off; off >>= 1) s += __shfl_xor(s, off);
    float mu = s * (1.0f / 128.0f);
    float v0 = y0 - mu, v1 = y1 - mu;
    float vs = v0 * v0 + v1 * v1;
#pragma unroll
    for (int off = 32; off; off >>= 1) vs += __shfl_xor(vs, off);
    float rstd = rsqrtf(vs * (1.0f / 128.0f) + 1e-5f);

    float2 gv = *(const float2*)(gamma + d2);
    float2 bv = *(const float2*)(beta + d2);
    float2 ov;
    ov.x = fmaxf(v0 * rstd * gv.x + bv.x, 0.0f);
    ov.y = fmaxf(v1 * rstd * gv.y + bv.y, 0.0f);
    *(float2*)(out + (size_t)(bt * NN + i) * DD + d2) = ov;
}

extern "C" void kernel_launch(void* const* d_in, const int* in_sizes, int n_in,
                              void* d_out, int out_size, void* d_ws, size_t ws_size,
                              hipStream_t stream) {
    const float* x      = (const float*)d_in[0];
    const float* adj    = (const float*)d_in[1];
    const float* weight = (const float*)d_in[2];
    const float* bias   = (const float*)d_in[3];
    const float* attw1  = (const float*)d_in[4];
    const float* attb1  = (const float*)d_in[5];
    const float* attw2  = (const float*)d_in[6];
    // d_in[7] = att_b2: uniform score shift -> cancels in softmax
    const float* gamma  = (const float*)d_in[8];
    const float* beta   = (const float*)d_in[9];
    float* out = (float*)d_out;

    char* p = (char*)d_ws;
    __bf16* hbuf = (__bf16*)p;        p += (size_t)MROWS * DD * 2;
    __bf16* abuf = (__bf16*)p;        p += (size_t)MROWS * DD * 2;
    __bf16* bbuf = (__bf16*)p;        p += (size_t)MROWS * DD * 2;
    int* nbr     = (int*)p;           p += (size_t)NN * 64 * 4;
    int* nbr_cnt = (int*)p;

    gemm2_kernel<<<MROWS / 16 * 2, 256, 0, stream>>>(x, weight, bias, attw1, attb1,
                                                     adj, hbuf, abuf, bbuf,
                                                     nbr, nbr_cnt);
    attn_kernel<<<NN / 4 * BT, 256, 0, stream>>>(hbuf, abuf, bbuf, x, nbr, nbr_cnt,
                                                 attw2, gamma, beta, out);
}